// Round 3
// baseline (274.070 us; speedup 1.0000x reference)
//
#include <hip/hip_runtime.h>

// BaseEncoder: x[B,F] fp32 -> out[B,F,32] fp32
//   out[...,0]   = (x < 0) ? 1 : 0
//   out[...,1+d] = bit (30-d) of bitcast(x)  (positions 0..30 exclude sign bit)
//
// Mapping: 1 thread per 4 output channels ("quad"), 8 quads per input element.
// Consecutive lanes write consecutive 16B -> perfectly coalesced 1KiB/wave
// store instructions. ILP=4: each thread processes 4 quads at chunk stride
// (chunk % 8 == 0 keeps the quad phase identical), issuing 4 independent
// loads then 4 independent nontemporal stores for memory-level parallelism.
// Nontemporal: 268MB streaming write >> 32MB L2 -- bypass pollution.
//
// NOTE: __builtin_nontemporal_store requires a clang native vector type,
// not HIP's float4 class -> use ext_vector_type(4).

typedef float f32x4 __attribute__((ext_vector_type(4)));

constexpr int ILP = 4;

__global__ __launch_bounds__(256) void base_encoder_ilp4(
    const float* __restrict__ x, f32x4* __restrict__ out, int chunk) {
  int i = blockIdx.x * blockDim.x + threadIdx.x;
  if (i >= chunk) return;

  int idx[ILP];
  float xv[ILP];
#pragma unroll
  for (int k = 0; k < ILP; ++k) {
    idx[k] = i + k * chunk;
    xv[k] = x[idx[k] >> 3];   // 8 adjacent lanes share a dword (L1 broadcast)
  }

  int j0 = (i & 7) << 2;      // base output channel (chunk%8==0 -> same all k)

#pragma unroll
  for (int k = 0; k < ILP; ++k) {
    unsigned r = __float_as_uint(xv[k]);
    f32x4 o;
    o.x = (float)((r >> (31 - j0)) & 1u);
    o.y = (float)((r >> (30 - j0)) & 1u);
    o.z = (float)((r >> (29 - j0)) & 1u);
    o.w = (float)((r >> (28 - j0)) & 1u);
    if (j0 == 0) o.x = (xv[k] < 0.0f) ? 1.0f : 0.0f;  // exact sign channel
    __builtin_nontemporal_store(o, &out[idx[k]]);
  }
}

// Fallback for sizes not divisible by ILP*8 (not hit for 4096x512).
__global__ __launch_bounds__(256) void base_encoder_simple(
    const float* __restrict__ x, f32x4* __restrict__ out, int n_quads) {
  int i = blockIdx.x * blockDim.x + threadIdx.x;
  if (i >= n_quads) return;
  float xv = x[i >> 3];
  unsigned r = __float_as_uint(xv);
  int j0 = (i & 7) << 2;
  f32x4 o;
  o.x = (float)((r >> (31 - j0)) & 1u);
  o.y = (float)((r >> (30 - j0)) & 1u);
  o.z = (float)((r >> (29 - j0)) & 1u);
  o.w = (float)((r >> (28 - j0)) & 1u);
  if (j0 == 0) o.x = (xv < 0.0f) ? 1.0f : 0.0f;
  __builtin_nontemporal_store(o, &out[i]);
}

extern "C" void kernel_launch(void* const* d_in, const int* in_sizes, int n_in,
                              void* d_out, int out_size, void* d_ws, size_t ws_size,
                              hipStream_t stream) {
  const float* x = (const float*)d_in[0];
  f32x4* out = (f32x4*)d_out;
  int n_elems = in_sizes[0];        // 4096*512 = 2,097,152
  int n_quads = n_elems * 8;        // float4 stores; == out_size/4
  const int block = 256;

  if (n_quads % (ILP * 8) == 0) {
    int chunk = n_quads / ILP;      // multiple of 8 -> quad phase constant
    int grid = (chunk + block - 1) / block;
    base_encoder_ilp4<<<grid, block, 0, stream>>>(x, out, chunk);
  } else {
    int grid = (n_quads + block - 1) / block;
    base_encoder_simple<<<grid, block, 0, stream>>>(x, out, n_quads);
  }
}

// Round 4
// 270.602 us; speedup vs baseline: 1.0128x; 1.0128x over previous
//
#include <hip/hip_runtime.h>

// BaseEncoder: x[B,F] fp32 -> out[B,F,32] fp32
//   out[...,0]   = (x < 0) ? 1 : 0
//   out[...,1+d] = bit (30-d) of bitcast(x)  (positions 0..30 exclude sign bit)
//
// R4: persistent grid-stride structure mimicking the rocclr fill kernel that
// sustains 6.36 TB/s on this chip: 2048 blocks x 256 threads, each thread
// streams 32 dwordx4 NT stores with constant address increments, batched
// 4-deep (4 independent loads, then 4 independent stores).
//
// Mapping: 8 threads per input element, 4 consecutive output channels each
// -> consecutive lanes store consecutive 16B (1 KiB/wave store instr).
// Grid stride is a multiple of 8, so each thread's channel phase j0 and its
// shift amounts are loop-invariant (hoisted to registers once).

typedef float f32x4 __attribute__((ext_vector_type(4)));

constexpr int BLOCK = 256;
constexpr int GRID = 2048;   // 8 blocks/CU on 256 CUs; stride = 524288 (mult of 8)
constexpr int BATCH = 4;

__global__ __launch_bounds__(BLOCK) void base_encoder_gs(
    const float* __restrict__ x, f32x4* __restrict__ out, int n_quads) {
  const int stride = GRID * BLOCK;            // compile-time, multiple of 8
  int tid = blockIdx.x * BLOCK + threadIdx.x;
  const int j0 = (tid & 7) << 2;              // loop-invariant channel phase
  const bool sign_lane = (j0 == 0);

  for (int base = tid; base < n_quads; base += BATCH * stride) {
    int idx[BATCH];
    float xv[BATCH];
#pragma unroll
    for (int k = 0; k < BATCH; ++k) {
      idx[k] = base + k * stride;
      xv[k] = (idx[k] < n_quads) ? x[idx[k] >> 3] : 0.0f;
    }
#pragma unroll
    for (int k = 0; k < BATCH; ++k) {
      if (idx[k] < n_quads) {
        unsigned r = __float_as_uint(xv[k]);
        f32x4 o;
        o.x = (float)((r >> (31 - j0)) & 1u);
        o.y = (float)((r >> (30 - j0)) & 1u);
        o.z = (float)((r >> (29 - j0)) & 1u);
        o.w = (float)((r >> (28 - j0)) & 1u);
        if (sign_lane) o.x = (xv[k] < 0.0f) ? 1.0f : 0.0f;  // exact sign channel
        __builtin_nontemporal_store(o, &out[idx[k]]);
      }
    }
  }
}

extern "C" void kernel_launch(void* const* d_in, const int* in_sizes, int n_in,
                              void* d_out, int out_size, void* d_ws, size_t ws_size,
                              hipStream_t stream) {
  const float* x = (const float*)d_in[0];
  f32x4* out = (f32x4*)d_out;
  int n_elems = in_sizes[0];        // 4096*512 = 2,097,152
  int n_quads = n_elems * 8;        // one float4 store per quad; == out_size/4
  base_encoder_gs<<<GRID, BLOCK, 0, stream>>>(x, out, n_quads);
}